// Round 4
// baseline (254.732 us; speedup 1.0000x reference)
//
#include <hip/hip_runtime.h>
#include <math.h>

#define BBATCH 64
#define LL 200
#define DD 300
#define PP 16
#define EPSV 1e-12f

#define LROW 208   // padded rows for h1
#define KP 320     // padded K
#define NJT 13     // j-tiles of 16 (208)
#define NKC 10     // k-chunks of 32

typedef _Float16 f16x8 __attribute__((ext_vector_type(8)));
typedef float f32x4v __attribute__((ext_vector_type(4)));

// ---------------- prep: fused norms + f16 conversion + frag-swizzle ----------------------
// grid (13, 2, 64). which=0: emit h1 (row-major f16, zero-padded) + n1inv.
//                   which=1: emit h2f (MFMA-A-frag-swizzled f16) + n2inv (+ ksqf once).
__global__ __launch_bounds__(256) void prep_kernel(const float* __restrict__ s1,
                                                   const float* __restrict__ s2,
                                                   const float* __restrict__ kern,
                                                   float* __restrict__ n1inv,
                                                   float* __restrict__ n2inv,
                                                   _Float16* __restrict__ h1,
                                                   _Float16* __restrict__ h2f,
                                                   _Float16* __restrict__ ksqf) {
    const int grp   = blockIdx.x;   // 0..12 (16-row group)
    const int which = blockIdx.y;
    const int b     = blockIdx.z;
    const float* s  = which ? s2 : s1;
    float* outp     = which ? n2inv : n1inv;

    __shared__ float rows[16][KP];  // 20 KB
    __shared__ float kl[16][KP];    // 20 KB
    const int t = threadIdx.x;

    // stage 16 rows + kernel, zero-padded to KP
    for (int idx = t; idx < 16 * 80; idx += 256) {
        int r  = idx / 80;
        int c4 = idx - r * 80;
        int d  = c4 * 4;
        int row = grp * 16 + r;
        float4 v = make_float4(0.f, 0.f, 0.f, 0.f);
        if (row < LL && d < DD) v = *(const float4*)&s[((size_t)b * LL + row) * DD + d];
        *(float4*)&rows[r][d] = v;
        float4 kv = make_float4(0.f, 0.f, 0.f, 0.f);
        if (d < DD) kv = *(const float4*)&kern[(size_t)r * DD + d];
        *(float4*)&kl[r][d] = kv;
    }
    __syncthreads();

    // norms: thread (r = t>>4, p = t&15)
    {
        const int r = t >> 4, p = t & 15;
        float acc = 0.f;
        for (int c4 = 0; c4 < 75; c4++) {
            float4 a = *(const float4*)&rows[r][c4 * 4];
            float4 k = *(const float4*)&kl[p][c4 * 4];
            float v0 = a.x * k.x, v1 = a.y * k.y, v2 = a.z * k.z, v3 = a.w * k.w;
            acc += v0 * v0 + v1 * v1 + v2 * v2 + v3 * v3;
        }
        int row = grp * 16 + r;
        if (row < LL) outp[((size_t)b * LL + row) * PP + p] = 1.0f / sqrtf(fmaxf(acc, EPSV));
    }

    // f16 emissions (rows[] already zero-padded; no further sync needed, rows is read-only now)
    if (which == 0) {
        for (int g = t; g < 640; g += 256) {
            int r = g / 40, pos = g - r * 40, d0 = pos * 8;
            float4 a = *(const float4*)&rows[r][d0];
            float4 c = *(const float4*)&rows[r][d0 + 4];
            f16x8 h;
            h[0] = (_Float16)a.x; h[1] = (_Float16)a.y; h[2] = (_Float16)a.z; h[3] = (_Float16)a.w;
            h[4] = (_Float16)c.x; h[5] = (_Float16)c.y; h[6] = (_Float16)c.z; h[7] = (_Float16)c.w;
            *(f16x8*)&h1[((size_t)b * LROW + grp * 16 + r) * KP + d0] = h;
        }
    } else {
        for (int g = t; g < 640; g += 256) {
            int r = g / 40, pos = g - r * 40, d0 = pos * 8;
            int kc = pos >> 2, q = pos & 3;
            float4 a = *(const float4*)&rows[r][d0];
            float4 c = *(const float4*)&rows[r][d0 + 4];
            f16x8 h;
            h[0] = (_Float16)a.x; h[1] = (_Float16)a.y; h[2] = (_Float16)a.z; h[3] = (_Float16)a.w;
            h[4] = (_Float16)c.x; h[5] = (_Float16)c.y; h[6] = (_Float16)c.z; h[7] = (_Float16)c.w;
            // h2f[b][jt=grp][kc][q][m=r][e] : frag-ready (lane reads 16B at lane*16)
            *(f16x8*)&h2f[(((size_t)b * NJT + grp) * NKC + kc) * 512 + (q * 16 + r) * 8] = h;
        }
        if (grp == 12) {   // emit ksq frags (64 blocks write identical data; benign)
            for (int g = t; g < 640; g += 256) {
                int p = g & 15, qk = g >> 4;
                int kc = qk >> 2, q = qk & 3;
                int k0 = kc * 32 + q * 8;
                float4 a = *(const float4*)&kl[p][k0];
                float4 c = *(const float4*)&kl[p][k0 + 4];
                f16x8 h;
                h[0] = (_Float16)(a.x * a.x); h[1] = (_Float16)(a.y * a.y);
                h[2] = (_Float16)(a.z * a.z); h[3] = (_Float16)(a.w * a.w);
                h[4] = (_Float16)(c.x * c.x); h[5] = (_Float16)(c.y * c.y);
                h[6] = (_Float16)(c.z * c.z); h[7] = (_Float16)(c.w * c.w);
                *(f16x8*)&ksqf[((kc * 4 + q) * 16 + p) * 8] = h;
            }
        }
    }
}

// ---------------- maxsim: C[j,p] = E·ksq^T per (b,i), E built in registers ---------------
// block = (b, 16-i group), 4 waves x 4 i. XCD-swizzled block id keeps each b's h2f on one XCD.
__global__ __launch_bounds__(256, 3) void maxsim_kernel(const _Float16* __restrict__ h1,
                                                        const _Float16* __restrict__ h2f,
                                                        const _Float16* __restrict__ ksqf,
                                                        const float* __restrict__ n1inv,
                                                        const float* __restrict__ n2inv,
                                                        float* __restrict__ out) {
    // decode swizzle: blocks of batch b all land on XCD b%8 (heuristic: xcd = blockIdx % 8)
    const int g  = blockIdx.x;        // 0..831
    const int r8 = g & 7;
    const int s  = g >> 3;            // 0..103
    const int bh = s / 13;
    const int ib = s - bh * 13;
    const int b  = bh * 8 + r8;
    const int i0 = ib * 16;

    __shared__ __align__(16) _Float16 h1s[16 * KP];   // 10240 B
    __shared__ __align__(16) _Float16 ksqs[5120];     // 10240 B
    __shared__ float n2s[LL * PP];                    // 12800 B

    const int t = threadIdx.x;
    {
        const _Float16* src = h1 + ((size_t)b * LROW + i0) * KP;
        for (int idx = t; idx < 640; idx += 256)
            *(f16x8*)&h1s[idx * 8] = *(const f16x8*)&src[idx * 8];
        for (int idx = t; idx < 640; idx += 256)
            *(f16x8*)&ksqs[idx * 8] = *(const f16x8*)&ksqf[idx * 8];
        const float* nsrc = n2inv + (size_t)b * LL * PP;
        for (int idx = t; idx < 800; idx += 256)
            *(float4*)&n2s[idx * 4] = *(const float4*)&nsrc[idx * 4];
    }
    __syncthreads();

    const int lane = t & 63;
    const int w    = t >> 6;       // wave id: i = i0 + w*4 + ii
    const int c    = lane & 15;
    const int quad = lane >> 4;

    const _Float16* h2b = h2f + (size_t)b * NJT * NKC * 512 + (size_t)lane * 8;

    float rmax[4] = {-INFINITY, -INFINITY, -INFINITY, -INFINITY};

#pragma unroll
    for (int jg = 0; jg < 4; jg++) {
        const int njt = (jg < 3) ? 4 : 1;   // 13 j-tiles total
        f32x4v acc[4][4];
#pragma unroll
        for (int ii = 0; ii < 4; ii++)
#pragma unroll
            for (int jtl = 0; jtl < 4; jtl++) acc[ii][jtl] = (f32x4v)0.f;

        f16x8 s2f[2][4];
#pragma unroll
        for (int jtl = 0; jtl < njt; jtl++)
            s2f[0][jtl] = *(const f16x8*)&h2b[((size_t)(jg * 4 + jtl) * NKC + 0) * 512];

#pragma unroll
        for (int kc = 0; kc < NKC; kc++) {
            const int cur = kc & 1, nxt = cur ^ 1;
            if (kc < NKC - 1) {   // prefetch next k-chunk's s2 frags (L2-resident)
#pragma unroll
                for (int jtl = 0; jtl < njt; jtl++)
                    s2f[nxt][jtl] = *(const f16x8*)&h2b[((size_t)(jg * 4 + jtl) * NKC + kc + 1) * 512];
            }
            f16x8 Bf = *(const f16x8*)&ksqs[(kc * 4 + quad) * 128 + c * 8];
            f16x8 s1f[4];
#pragma unroll
            for (int ii = 0; ii < 4; ii++)
                s1f[ii] = *(const f16x8*)&h1s[(w * 4 + ii) * KP + kc * 32 + quad * 8];

#pragma unroll
            for (int jtl = 0; jtl < njt; jtl++) {
#pragma unroll
                for (int ii = 0; ii < 4; ii++) {
                    f16x8 af = s2f[cur][jtl] * s1f[ii];   // 4 v_pk_mul_f16: E-frag in regs
                    acc[ii][jtl] = __builtin_amdgcn_mfma_f32_16x16x32_f16(af, Bf, acc[ii][jtl], 0, 0, 0);
                }
            }
        }

        // epilogue: scale by n2inv[j,p], fold max over j-rows (C/D: col=lane&15=p, row=quad*4+r=j_local)
#pragma unroll
        for (int jtl = 0; jtl < njt; jtl++) {
            int jt = jg * 4 + jtl;
#pragma unroll
            for (int r = 0; r < 4; r++) {
                int j = jt * 16 + quad * 4 + r;
                if (j < LL) {
                    float n2 = n2s[j * PP + c];
#pragma unroll
                    for (int ii = 0; ii < 4; ii++)
                        rmax[ii] = fmaxf(rmax[ii], acc[ii][jtl][r] * n2);
                }
            }
        }
    }

    // reduce across quads (each lane's col p is fixed; rows j live across quads)
#pragma unroll
    for (int ii = 0; ii < 4; ii++) {
        rmax[ii] = fmaxf(rmax[ii], __shfl_xor(rmax[ii], 16));
        rmax[ii] = fmaxf(rmax[ii], __shfl_xor(rmax[ii], 32));
    }

    if (lane < 16) {   // lane = p
#pragma unroll
        for (int ii = 0; ii < 4; ii++) {
            int i = i0 + w * 4 + ii;
            if (i < LL) {
                size_t o = ((size_t)b * LL + i) * PP + lane;
                out[o] = rmax[ii] * n1inv[o];
            }
        }
    }
}

extern "C" void kernel_launch(void* const* d_in, const int* in_sizes, int n_in,
                              void* d_out, int out_size, void* d_ws, size_t ws_size,
                              hipStream_t stream) {
    const float* sent1  = (const float*)d_in[0];   // (64,200,300) f32
    const float* sent2  = (const float*)d_in[1];   // (64,200,300) f32
    const float* kernel = (const float*)d_in[2];   // (16,300)     f32
    float* out = (float*)d_out;                    // (64,200,16)  f32

    float*    n1inv = (float*)d_ws;                                   // 204800 f32
    float*    n2inv = n1inv + (size_t)BBATCH * LL * PP;               // 204800 f32
    _Float16* h1    = (_Float16*)(n2inv + (size_t)BBATCH * LL * PP);  // 64*208*320 halfs
    _Float16* h2f   = h1 + (size_t)BBATCH * LROW * KP;                // 64*13*10*512 halfs
    _Float16* ksqf  = h2f + (size_t)BBATCH * NJT * NKC * 512;         // 5120 halfs
    // total ws: ~17.9 MB

    prep_kernel<<<dim3(13, 2, BBATCH), 256, 0, stream>>>(sent1, sent2, kernel,
                                                         n1inv, n2inv, h1, h2f, ksqf);
    maxsim_kernel<<<dim3(NJT * BBATCH, 1, 1), 256, 0, stream>>>(h1, h2f, ksqf,
                                                                n1inv, n2inv, out);
}

// Round 5
// 189.753 us; speedup vs baseline: 1.3424x; 1.3424x over previous
//
#include <hip/hip_runtime.h>
#include <math.h>

#define BBATCH 64
#define LL 200
#define DD 300
#define PP 16
#define EPSV 1e-12f
#define KG 320          // global K-pad (10 chunks of 32)
#define PS 328          // LDS row stride in halfs (656 B: 4-bank row shift, 2-way alias = free)
#define NCH 10

typedef _Float16 f16x8 __attribute__((ext_vector_type(8)));
typedef float f32x4v __attribute__((ext_vector_type(4)));

// ---------------- prep: norms + one-time f16 conversion + ksq frag table ----------------
// grid (13, 2, 64). which=0: h1=f16(s1), n1inv(f32). which=1: h2=f16(s2), n2inv(f16);
// (which==1,grp==12) also emits ksqt = f16(kp^2) in B-frag layout.
__global__ __launch_bounds__(256) void prep_kernel(const float* __restrict__ s1,
                                                   const float* __restrict__ s2,
                                                   const float* __restrict__ kern,
                                                   float* __restrict__ n1inv,
                                                   _Float16* __restrict__ n2inv,
                                                   _Float16* __restrict__ h1,
                                                   _Float16* __restrict__ h2,
                                                   _Float16* __restrict__ ksqt) {
    const int grp   = blockIdx.x;   // 0..12 (16-row groups)
    const int which = blockIdx.y;
    const int b     = blockIdx.z;
    const float* s  = which ? s2 : s1;
    _Float16* hout  = which ? h2 : h1;
    const int r0    = grp * 16;
    const int t     = threadIdx.x;

    __shared__ float rows[16][KG];   // 20 KB, zero-padded
    __shared__ float kl[16][324];    // padded stride: 4-bank row shift

    for (int idx = t; idx < 16 * 80; idx += 256) {
        int r = idx / 80, c4 = (idx - r * 80) * 4;
        float4 kv = make_float4(0.f, 0.f, 0.f, 0.f);
        if (c4 < DD) kv = *(const float4*)&kern[r * DD + c4];
        *(float4*)&kl[r][c4] = kv;
    }
    for (int idx = t; idx < 16 * 80; idx += 256) {
        int r = idx / 80, c4 = (idx - r * 80) * 4;
        int row = r0 + r;
        float4 v = make_float4(0.f, 0.f, 0.f, 0.f);
        if (row < LL && c4 < DD) v = *(const float4*)&s[((size_t)b * LL + row) * DD + c4];
        *(float4*)&rows[r][c4] = v;
    }
    __syncthreads();

    // norms: thread (r=t>>4, p=t&15); rows[] broadcast (same addr per 16 lanes)
    {
        int r = t >> 4, p = t & 15;
        int row = r0 + r;
        float acc = 0.f;
#pragma unroll 5
        for (int c4 = 0; c4 < 80; c4++) {
            float4 a = *(const float4*)&rows[r][c4 * 4];
            float4 k = *(const float4*)&kl[p][c4 * 4];
            float v0 = a.x * k.x, v1 = a.y * k.y, v2 = a.z * k.z, v3 = a.w * k.w;
            acc += v0 * v0 + v1 * v1 + v2 * v2 + v3 * v3;
        }
        if (row < LL) {
            float inv = 1.0f / sqrtf(fmaxf(acc, EPSV));
            if (which) n2inv[((size_t)b * LL + row) * PP + p] = (_Float16)inv;
            else       n1inv[((size_t)b * LL + row) * PP + p] = inv;
        }
    }

    // emit f16 rows (row-major, K-padded to 320)
    for (int idx = t; idx < 640; idx += 256) {
        int r = idx / 40, q8 = (idx - r * 40) * 8;
        int row = r0 + r;
        if (row < LL) {
            float4 a = *(const float4*)&rows[r][q8];
            float4 d = *(const float4*)&rows[r][q8 + 4];
            f16x8 h;
            h[0] = (_Float16)a.x; h[1] = (_Float16)a.y; h[2] = (_Float16)a.z; h[3] = (_Float16)a.w;
            h[4] = (_Float16)d.x; h[5] = (_Float16)d.y; h[6] = (_Float16)d.z; h[7] = (_Float16)d.w;
            *(f16x8*)&hout[((size_t)b * LL + row) * KG + q8] = h;
        }
    }

    // ksq frag table: ksqt[((ch*4+quad)*16+p)*8 + e] = f16(kp[p][ch*32+quad*8+e]^2)
    if (which == 1 && grp == 12) {
        for (int ent = t; ent < 640; ent += 256) {
            int ch = ent / 64, rem = ent - ch * 64;
            int quad = rem >> 4, p = rem & 15;
            int k0 = ch * 32 + quad * 8;
            float4 a = *(const float4*)&kl[p][k0];
            float4 d = *(const float4*)&kl[p][k0 + 4];
            f16x8 h;
            h[0] = (_Float16)(a.x * a.x); h[1] = (_Float16)(a.y * a.y);
            h[2] = (_Float16)(a.z * a.z); h[3] = (_Float16)(a.w * a.w);
            h[4] = (_Float16)(d.x * d.x); h[5] = (_Float16)(d.y * d.y);
            h[6] = (_Float16)(d.z * d.z); h[7] = (_Float16)(d.w * d.w);
            *(f16x8*)&ksqt[(size_t)ent * 8] = h;
        }
    }
}

// ---------------- maxsim: full-K LDS-resident tiles, p-loop inside ----------------------
// block = (b, iblk, jblk): A 128i x 320k, B 112j x 320k f16 in LDS (161 KB, 1 block/CU).
// For each p: C = A ⊙ (B*ksq_p)ᵀ via MFMA, scale cols by n2, fold max over j → part.
// Overlapped windows (iblk1@72, jblk1@88) cover 0..199 with no padding masks.
__global__ __launch_bounds__(256, 1) void maxsim_kernel(const _Float16* __restrict__ h1,
                                                        const _Float16* __restrict__ h2,
                                                        const _Float16* __restrict__ ksqt,
                                                        const _Float16* __restrict__ n2inv,
                                                        float* __restrict__ part) {
    extern __shared__ __align__(16) char smem[];
    _Float16* h1s = (_Float16*)smem;          // 128*PS halfs
    _Float16* h2s = h1s + 128 * PS;           // 112*PS halfs
    _Float16* n2s = h2s + 112 * PS;           // 112*16 halfs

    const int blk  = blockIdx.x;
    const int b    = blk >> 2;
    const int iblk = (blk >> 1) & 1;
    const int jblk = blk & 1;
    const int i0   = iblk ? 72 : 0;
    const int j0   = jblk ? 88 : 0;
    const int t    = threadIdx.x;

    // stage tiles (row-contiguous global -> padded-stride LDS)
    {
        const _Float16* g1 = h1 + ((size_t)b * LL + i0) * KG;
        for (int idx = t; idx < 128 * 40; idx += 256) {
            int r = idx / 40, q = idx - r * 40;
            *(f16x8*)&h1s[r * PS + q * 8] = *(const f16x8*)&g1[(size_t)idx * 8];
        }
        const _Float16* g2 = h2 + ((size_t)b * LL + j0) * KG;
        for (int idx = t; idx < 112 * 40; idx += 256) {
            int r = idx / 40, q = idx - r * 40;
            *(f16x8*)&h2s[r * PS + q * 8] = *(const f16x8*)&g2[(size_t)idx * 8];
        }
        const _Float16* gn = n2inv + ((size_t)b * LL + j0) * PP;
        for (int idx = t; idx < 224; idx += 256)
            *(f16x8*)&n2s[idx * 8] = *(const f16x8*)&gn[idx * 8];
    }
    __syncthreads();

    const int lane = t & 63;
    const int w    = t >> 6;      // wave: i rows [w*32, w*32+32)
    const int c    = lane & 15;
    const int quad = lane >> 4;

    for (int pp = 0; pp < 8; pp++) {
        const int p0 = pp * 2;
        f32x4v acc[2][2][7];      // [p][it][jt]
#pragma unroll
        for (int pq = 0; pq < 2; pq++)
#pragma unroll
            for (int it = 0; it < 2; it++)
#pragma unroll
                for (int jt = 0; jt < 7; jt++) acc[pq][it][jt] = (f32x4v)0.f;

        f16x8 kq[2][2];
        kq[0][0] = *(const f16x8*)&ksqt[quad * 128 + p0 * 8];
        kq[0][1] = *(const f16x8*)&ksqt[quad * 128 + p0 * 8 + 8];

#pragma unroll
        for (int ch = 0; ch < NCH; ch++) {
            const int cur = ch & 1, nxt = cur ^ 1;
            if (ch < NCH - 1) {   // prefetch next chunk's ksq frags (L2-hot 10 KB table)
                kq[nxt][0] = *(const f16x8*)&ksqt[(ch + 1) * 512 + quad * 128 + p0 * 8];
                kq[nxt][1] = *(const f16x8*)&ksqt[(ch + 1) * 512 + quad * 128 + p0 * 8 + 8];
            }
            f16x8 af0 = *(const f16x8*)&h1s[(w * 32 + c) * PS + ch * 32 + quad * 8];
            f16x8 af1 = *(const f16x8*)&h1s[(w * 32 + 16 + c) * PS + ch * 32 + quad * 8];
#pragma unroll
            for (int jt = 0; jt < 7; jt++) {
                f16x8 hb = *(const f16x8*)&h2s[(jt * 16 + c) * PS + ch * 32 + quad * 8];
                f16x8 sb0 = hb * kq[cur][0];
                f16x8 sb1 = hb * kq[cur][1];
                acc[0][0][jt] = __builtin_amdgcn_mfma_f32_16x16x32_f16(af0, sb0, acc[0][0][jt], 0, 0, 0);
                acc[0][1][jt] = __builtin_amdgcn_mfma_f32_16x16x32_f16(af1, sb0, acc[0][1][jt], 0, 0, 0);
                acc[1][0][jt] = __builtin_amdgcn_mfma_f32_16x16x32_f16(af0, sb1, acc[1][0][jt], 0, 0, 0);
                acc[1][1][jt] = __builtin_amdgcn_mfma_f32_16x16x32_f16(af1, sb1, acc[1][1][jt], 0, 0, 0);
            }
        }

        // epilogue: scale by n2[j,p], max over j (C/D: col=lane&15=j, row=quad*4+r=i-local)
#pragma unroll
        for (int pq = 0; pq < 2; pq++) {
            const int p = p0 + pq;
            float rmax[2][4];
#pragma unroll
            for (int it = 0; it < 2; it++)
#pragma unroll
                for (int r = 0; r < 4; r++) rmax[it][r] = -INFINITY;

#pragma unroll
            for (int jt = 0; jt < 7; jt++) {
                float n2 = (float)n2s[(jt * 16 + c) * PP + p];
#pragma unroll
                for (int it = 0; it < 2; it++)
#pragma unroll
                    for (int r = 0; r < 4; r++)
                        rmax[it][r] = fmaxf(rmax[it][r], acc[pq][it][jt][r] * n2);
            }
#pragma unroll
            for (int m = 1; m <= 8; m <<= 1)
#pragma unroll
                for (int it = 0; it < 2; it++)
#pragma unroll
                    for (int r = 0; r < 4; r++)
                        rmax[it][r] = fmaxf(rmax[it][r], __shfl_xor(rmax[it][r], m));

            if (c == 0) {
#pragma unroll
                for (int it = 0; it < 2; it++)
#pragma unroll
                    for (int r = 0; r < 4; r++) {
                        int i = i0 + w * 32 + it * 16 + quad * 4 + r;   // < 200 by construction
                        part[((size_t)jblk * BBATCH + b) * (LL * PP) + (size_t)i * PP + p] = rmax[it][r];
                    }
            }
        }
    }
}

// ---------------- reduce: out = max(part0, part1) * n1inv --------------------------------
__global__ __launch_bounds__(256) void reduce_kernel(const float* __restrict__ part,
                                                     const float* __restrict__ n1inv,
                                                     float* __restrict__ out) {
    int tid = blockIdx.x * 256 + threadIdx.x;
    if (tid >= BBATCH * LL * PP) return;
    out[tid] = fmaxf(part[tid], part[(size_t)BBATCH * LL * PP + tid]) * n1inv[tid];
}

extern "C" void kernel_launch(void* const* d_in, const int* in_sizes, int n_in,
                              void* d_out, int out_size, void* d_ws, size_t ws_size,
                              hipStream_t stream) {
    const float* sent1  = (const float*)d_in[0];   // (64,200,300) f32
    const float* sent2  = (const float*)d_in[1];   // (64,200,300) f32
    const float* kernel = (const float*)d_in[2];   // (16,300)     f32
    float* out = (float*)d_out;                    // (64,200,16)  f32

    char* ws = (char*)d_ws;
    float*    n1inv = (float*)ws;                  ws += (size_t)BBATCH * LL * PP * 4;   // 0.82 MB
    _Float16* n2inv = (_Float16*)ws;               ws += (size_t)BBATCH * LL * PP * 2;   // 0.41 MB
    _Float16* h1    = (_Float16*)ws;               ws += (size_t)BBATCH * LL * KG * 2;   // 8.19 MB
    _Float16* h2    = (_Float16*)ws;               ws += (size_t)BBATCH * LL * KG * 2;   // 8.19 MB
    _Float16* ksqt  = (_Float16*)ws;               ws += (size_t)640 * 8 * 2;            // 10 KB
    float*    part  = (float*)ws;                  // 2*64*200*16 f32 = 1.64 MB (total ~19.3 MB)

    prep_kernel<<<dim3(13, 2, BBATCH), 256, 0, stream>>>(sent1, sent2, kernel,
                                                         n1inv, n2inv, h1, h2, ksqt);

    const int lds_bytes = (128 * PS + 112 * PS + 112 * PP) * 2;   // 161,024 B
    hipFuncSetAttribute((const void*)maxsim_kernel,
                        hipFuncAttributeMaxDynamicSharedMemorySize, lds_bytes);
    maxsim_kernel<<<dim3(256, 1, 1), 256, lds_bytes, stream>>>(h1, h2, ksqt, n2inv, part);

    int nout = BBATCH * LL * PP;
    reduce_kernel<<<(nout + 255) / 256, 256, 0, stream>>>(part, n1inv, out);
}